// Round 7
// baseline (763.891 us; speedup 1.0000x reference)
//
#include <hip/hip_runtime.h>
#include <hip/hip_bf16.h>

#define NEG_SLOPE 0.1f
#define D1 128
#define D2 256

__device__ __forceinline__ float leaky(float x) { return x >= 0.f ? x : NEG_SLOPE * x; }

__device__ __forceinline__ unsigned short f2bf(float x) {
    union { float f; unsigned int u; } v; v.f = x;
    unsigned int r = (v.u + 0x7FFFu + ((v.u >> 16) & 1u)) >> 16;   // RNE
    return (unsigned short)r;
}

// ---- stage 1: per-edge stats, fully XCD-privatized (agent-scope atomics stay in
// the local L2 -- measured R6: non-write-through, ~0 HBM write traffic).
// rowstats8: packed u64 (count << 42 | fixed-point(abs_sum, 2^-24)) per XCD.
// col_cnt8:  per-XCD column histogram; returned value = local rank within (xcc,c),
//            packed into rank[e] = (xcc << 28) | local_rank  (E < 2^28).
__global__ void k_edge_stats(const int* __restrict__ row, const int* __restrict__ col,
                             const float* __restrict__ val,
                             unsigned long long* __restrict__ rowstats8,
                             unsigned int* __restrict__ col_cnt8,
                             int* __restrict__ rank, int E, int N)
{
    int e = blockIdx.x * blockDim.x + threadIdx.x;
    if (e >= E) return;
    // HW_REG_XCC_ID = 20, offset 0, size 32 -> simm16 = (31<<11)|20 = 63508
    unsigned xcc = (unsigned)__builtin_amdgcn_s_getreg(63508) & 7u;
    int r = row[e], c = col[e];
    float av = fabsf(val[e]);
    unsigned long long pk = (1ULL << 42) |
        (unsigned long long)__float2uint_rn(av * 16777216.0f);   // 2^24 fixed point
    __hip_atomic_fetch_add(&rowstats8[(size_t)xcc * N + r], pk,
                           __ATOMIC_RELAXED, __HIP_MEMORY_SCOPE_AGENT);
    unsigned lr = __hip_atomic_fetch_add(&col_cnt8[(size_t)xcc * N + c], 1u,
                                         __ATOMIC_RELAXED, __HIP_MEMORY_SCOPE_AGENT);
    rank[e] = (int)((xcc << 28) | lr);
}

// ---- stage 2a: combine 8 per-XCD row stats; per-node abs_mean, deg, dinv, self pv ----
__global__ void k_node_stats(const unsigned long long* __restrict__ rowstats8,
                             float* __restrict__ dinv, float* __restrict__ pv_self, int N)
{
    int i = blockIdx.x * blockDim.x + threadIdx.x;
    if (i >= N) return;
    unsigned long long t = 0;
#pragma unroll
    for (int x = 0; x < 8; x++) t += rowstats8[(size_t)x * N + i];
    float c  = (float)(t >> 42);
    float as = (float)(t & ((1ULL << 42) - 1)) * (1.0f / 16777216.0f);
    float am = as / fmaxf(c, 1.0f);
    float deg = as + am;
    float di  = deg > 0.f ? rsqrtf(deg) : 0.f;
    dinv[i]    = di;
    pv_self[i] = am * di * di;
}

// ---- stage 2b: per-node exclusive prefix over the 8 XCD histograms (in place ->
// per-XCD base) and total count -> col_cnt ----
__global__ void k_combine_cols(unsigned int* __restrict__ col_cnt8,
                               int* __restrict__ col_cnt, int N)
{
    int i = blockIdx.x * blockDim.x + threadIdx.x;
    if (i >= N) return;
    unsigned tot = 0;
#pragma unroll
    for (int x = 0; x < 8; x++) {
        unsigned t = col_cnt8[(size_t)x * N + i];
        col_cnt8[(size_t)x * N + i] = tot;
        tot += t;
    }
    col_cnt[i] = (int)tot;
}

// ---- exclusive scan of col_cnt -> col_ptr ----
__global__ __launch_bounds__(256) void k_scan_local(const int* __restrict__ in, int* __restrict__ out,
                                                    int* __restrict__ partials, int n)
{
    __shared__ int s[256];
    int base = blockIdx.x * 2048 + threadIdx.x * 8;
    int v[8]; int sum = 0;
#pragma unroll
    for (int i = 0; i < 8; i++) { v[i] = (base + i < n) ? in[base + i] : 0; sum += v[i]; }
    s[threadIdx.x] = sum;
    __syncthreads();
    for (int off = 1; off < 256; off <<= 1) {
        int t = (threadIdx.x >= off) ? s[threadIdx.x - off] : 0;
        __syncthreads();
        s[threadIdx.x] += t;
        __syncthreads();
    }
    int excl = s[threadIdx.x] - sum;
#pragma unroll
    for (int i = 0; i < 8; i++) { if (base + i < n) { out[base + i] = excl; excl += v[i]; } }
    if (threadIdx.x == 255) partials[blockIdx.x] = s[255];
}

__global__ void k_scan_partials(int* __restrict__ partials, int nb, int* __restrict__ col_ptr,
                                int n, int total)
{
    if (threadIdx.x == 0) {
        int run = 0;
        for (int i = 0; i < nb; i++) { int t = partials[i]; partials[i] = run; run += t; }
        col_ptr[n] = total;
    }
}

__global__ void k_scan_add(int* __restrict__ out, const int* __restrict__ partials, int n)
{
    int i = blockIdx.x * blockDim.x + threadIdx.x;
    if (i < n) out[i] += partials[i >> 11];
}

// ---- scatter edges into dest-sorted CSR using precomputed ranks (no atomics) ----
__global__ void k_scatter(const int* __restrict__ row, const int* __restrict__ col,
                          const float* __restrict__ val, const float* __restrict__ dinv,
                          const int* __restrict__ col_ptr, const unsigned int* __restrict__ col_cnt8,
                          const int* __restrict__ rank,
                          int2* __restrict__ srt_rp, int E, int N)
{
    int e = blockIdx.x * blockDim.x + threadIdx.x;
    if (e >= E) return;
    int r = row[e], c = col[e];
    float p = val[e] * dinv[r] * dinv[c];
    int rk = rank[e];
    unsigned xcc = (unsigned)rk >> 28;
    int lr = rk & 0x0FFFFFFF;
    int pos = col_ptr[c] + (int)col_cnt8[(size_t)xcc * N + c] + lr;
    srt_rp[pos] = make_int2(r, __float_as_int(p));
}

// ---- x1[i] = pv_self[i] + sum of pv over CSR range ----
__global__ void k_x1(const int* __restrict__ col_ptr, const int2* __restrict__ srt_rp,
                     const float* __restrict__ pv_self, float* __restrict__ x1, int N)
{
    int i = blockIdx.x * blockDim.x + threadIdx.x;
    if (i >= N) return;
    int s = col_ptr[i], e = col_ptr[i + 1];
    float acc = pv_self[i];
    for (int j = s; j < e; j++) acc += __int_as_float(srt_rp[j].y);
    x1[i] = acc;
}

// ---- pack edge-aligned (pv, x1[row]) stream for the scalar conv2 propagate ----
__global__ void k_gather_x1(const int2* __restrict__ srt_rp,
                            const float* __restrict__ x1, float2* __restrict__ px, int E)
{
    int j = blockIdx.x * blockDim.x + threadIdx.x;
    if (j >= E) return;
    int2 rp = srt_rp[j];
    px[j] = make_float2(__int_as_float(rp.y), x1[rp.x]);
}

// ---- conv2 propagate, scalar form:
// p2[i,d] = pv_self[i]*f_d(x1[i]) + sum_j pv_j * f_d(x1[r_j]),  f_d(s)=leaky(s*w1[d]+b1[d])
__global__ __launch_bounds__(256) void k_prop2(const int* __restrict__ col_ptr,
                                               const float2* __restrict__ px,
                                               const float* __restrict__ pv_self,
                                               const float* __restrict__ x1,
                                               const float* __restrict__ w1,
                                               const float* __restrict__ b1,
                                               float* __restrict__ p2, int N)
{
    int node = blockIdx.x * 2 + (threadIdx.x >> 7);
    int d = threadIdx.x & 127;
    if (node >= N) return;
    float wd = w1[d], bd = b1[d];
    float acc = pv_self[node] * leaky(fmaf(x1[node], wd, bd));
    int s = col_ptr[node], e = col_ptr[node + 1];
    for (int j = s; j < e; j++) {
        float2 t = px[j];
        acc += t.x * leaky(fmaf(t.y, wd, bd));
    }
    p2[(size_t)node * D1 + d] = acc;
}

// ---- conv3 gather propagate over bf16 z, one wave per node, 2 dims per lane ----
__global__ __launch_bounds__(256) void k_prop3_bf16(const int* __restrict__ col_ptr,
                                                    const int2* __restrict__ srt_rp,
                                                    const float* __restrict__ pv_self,
                                                    const unsigned int* __restrict__ zb,
                                                    const float* __restrict__ bias3,
                                                    float* __restrict__ out, int N)
{
    int node = blockIdx.x * 4 + (threadIdx.x >> 6);
    int lane = threadIdx.x & 63;
    if (node >= N) return;

    unsigned int us = zb[(size_t)node * 64 + lane];
    float ps = pv_self[node];
    float acc0 = ps * __uint_as_float(us << 16);
    float acc1 = ps * __uint_as_float(us & 0xFFFF0000u);

    int j = col_ptr[node], e = col_ptr[node + 1];
    for (; j + 1 < e; j += 2) {
        int2 rp0 = srt_rp[j];
        int2 rp1 = srt_rp[j + 1];
        unsigned int u0 = zb[(size_t)rp0.x * 64 + lane];
        unsigned int u1 = zb[(size_t)rp1.x * 64 + lane];
        float p0 = __int_as_float(rp0.y);
        float p1 = __int_as_float(rp1.y);
        acc0 += p0 * __uint_as_float(u0 << 16);
        acc1 += p0 * __uint_as_float(u0 & 0xFFFF0000u);
        acc0 += p1 * __uint_as_float(u1 << 16);
        acc1 += p1 * __uint_as_float(u1 & 0xFFFF0000u);
    }
    if (j < e) {
        int2 rp = srt_rp[j];
        unsigned int u = zb[(size_t)rp.x * 64 + lane];
        float p = __int_as_float(rp.y);
        acc0 += p * __uint_as_float(u << 16);
        acc1 += p * __uint_as_float(u & 0xFFFF0000u);
    }

    float2 b = *(const float2*)&bias3[lane * 2];
    float2 o = make_float2(leaky(acc0 + b.x), leaky(acc1 + b.y));
    *(float2*)&out[(size_t)node * D1 + lane * 2] = o;
}

// ---- tiled fp32 GEMM: C[N x M] = X[N x K] * W^T (+ epilogue), W is (M,K) row-major
template<int K, int M, bool LEAKY, bool X1B, bool BF16OUT>
__global__ __launch_bounds__(256) void k_gemm_t(const float* __restrict__ X,
                                                const float* __restrict__ W,
                                                const float* __restrict__ bvec,
                                                const float* __restrict__ bias,
                                                const float* __restrict__ x1,
                                                void* __restrict__ Cv, int N)
{
    __shared__ float Xs[16][64];   // [k][node]
    __shared__ float Ws[16][64];   // [k][col]

    const int tid = threadIdx.x;
    const int tc  = tid & 15;
    const int tr  = tid >> 4;
    const int n_base = blockIdx.x * 64;
    const int m_base = blockIdx.y * 64;

    float acc[4][4] = {};

    const int ld_row = tid >> 2;
    const int ld_k4  = (tid & 3) * 4;
    const int xnode  = n_base + ld_row;
    const bool xok   = xnode < N;
    const float* Xrow = X + (size_t)xnode * K + ld_k4;
    const float* Wrow = W + (size_t)(m_base + ld_row) * K + ld_k4;

    for (int k0 = 0; k0 < K; k0 += 16) {
        float4 xv = xok ? *(const float4*)(Xrow + k0) : make_float4(0.f, 0.f, 0.f, 0.f);
        float4 wv = *(const float4*)(Wrow + k0);
        __syncthreads();
        Xs[ld_k4 + 0][ld_row] = xv.x;
        Xs[ld_k4 + 1][ld_row] = xv.y;
        Xs[ld_k4 + 2][ld_row] = xv.z;
        Xs[ld_k4 + 3][ld_row] = xv.w;
        Ws[ld_k4 + 0][ld_row] = wv.x;
        Ws[ld_k4 + 1][ld_row] = wv.y;
        Ws[ld_k4 + 2][ld_row] = wv.z;
        Ws[ld_k4 + 3][ld_row] = wv.w;
        __syncthreads();
#pragma unroll
        for (int k = 0; k < 16; k++) {
            float4 a = *(const float4*)&Xs[k][tr * 4];
            float4 b = *(const float4*)&Ws[k][tc * 4];
            acc[0][0] += a.x * b.x; acc[0][1] += a.x * b.y; acc[0][2] += a.x * b.z; acc[0][3] += a.x * b.w;
            acc[1][0] += a.y * b.x; acc[1][1] += a.y * b.y; acc[1][2] += a.y * b.z; acc[1][3] += a.y * b.w;
            acc[2][0] += a.z * b.x; acc[2][1] += a.z * b.y; acc[2][2] += a.z * b.z; acc[2][3] += a.z * b.w;
            acc[3][0] += a.w * b.x; acc[3][1] += a.w * b.y; acc[3][2] += a.w * b.z; acc[3][3] += a.w * b.w;
        }
    }

#pragma unroll
    for (int ii = 0; ii < 4; ii++) {
        int node = n_base + tr * 4 + ii;
        if (node >= N) continue;
        float x1v = X1B ? x1[node] : 0.f;
        float vout[4];
#pragma unroll
        for (int jj = 0; jj < 4; jj++) {
            int m = m_base + tc * 4 + jj;
            float v = acc[ii][jj];
            if (X1B) v += x1v * bvec[m] + bias[m];
            else     v += bvec[m];
            if (LEAKY) v = leaky(v);
            vout[jj] = v;
        }
        if (BF16OUT) {
            ushort4 s4;
            s4.x = f2bf(vout[0]); s4.y = f2bf(vout[1]);
            s4.z = f2bf(vout[2]); s4.w = f2bf(vout[3]);
            *(ushort4*)((unsigned short*)Cv + (size_t)node * M + m_base + tc * 4) = s4;
        } else {
            *(float4*)((float*)Cv + (size_t)node * M + m_base + tc * 4) =
                make_float4(vout[0], vout[1], vout[2], vout[3]);
        }
    }
}

extern "C" void kernel_launch(void* const* d_in, const int* in_sizes, int n_in,
                              void* d_out, int out_size, void* d_ws, size_t ws_size,
                              hipStream_t stream)
{
    const int* ei       = (const int*)d_in[0];     // (2,E) int32
    const float* val    = (const float*)d_in[1];   // (E,)
    const float* w1     = (const float*)d_in[3];   // (128,1)
    const float* b1     = (const float*)d_in[4];   // (128,)
    const float* w2     = (const float*)d_in[5];   // (256,128)
    const float* b2     = (const float*)d_in[6];   // (256,)
    const float* bias2  = (const float*)d_in[7];   // (256,)
    const float* w3     = (const float*)d_in[8];   // (128,256)
    const float* b3     = (const float*)d_in[9];   // (128,)
    const float* bias3  = (const float*)d_in[10];  // (128,)
    float* out = (float*)d_out;

    const int E = in_sizes[1];
    const int N = out_size / D1;
    const int* row = ei;
    const int* col = ei + E;

    // workspace layout
    unsigned long long* rowstats8 = (unsigned long long*)d_ws;       // 8*N u64 (zeroed)
    unsigned int* col_cnt8 = (unsigned int*)(rowstats8 + (size_t)8 * N); // 8*N u32 (zeroed)
    int*   col_cnt = (int*)(col_cnt8 + (size_t)8 * N);               // N
    float* dinv    = (float*)(col_cnt + N);                          // N
    float* pv_self = dinv + N;                                       // N
    float* x1      = pv_self + N;                                    // N
    int*   col_ptr = (int*)(x1 + N);                                 // N+1
    int*   partials= col_ptr + N + 8;                                // 64
    int*   rank    = partials + 64;                                  // E
    int2*  srt_rp  = (int2*)(rank + E);                              // E int2
    float2* px     = (float2*)(srt_rp + (size_t)E);                  // E float2
    float* p2      = (float*)(px + (size_t)E);                       // N*128 fp32
    float* h2      = p2 + (size_t)N * D1;                            // N*256 fp32
    unsigned int* zb = (unsigned int*)p2;                            // bf16 z aliases dead p2

    hipMemsetAsync(d_ws, 0, (size_t)8 * N * 8 + (size_t)8 * N * 4, stream);

    const int B = 256;
    const int scan_blocks = (N + 2047) / 2048;

    k_edge_stats<<<(E + B - 1) / B, B, 0, stream>>>(row, col, val, rowstats8, col_cnt8, rank, E, N);
    k_node_stats<<<(N + B - 1) / B, B, 0, stream>>>(rowstats8, dinv, pv_self, N);
    k_combine_cols<<<(N + B - 1) / B, B, 0, stream>>>(col_cnt8, col_cnt, N);

    k_scan_local<<<scan_blocks, 256, 0, stream>>>(col_cnt, col_ptr, partials, N);
    k_scan_partials<<<1, 64, 0, stream>>>(partials, scan_blocks, col_ptr, N, E);
    k_scan_add<<<(N + B - 1) / B, B, 0, stream>>>(col_ptr, partials, N);

    k_scatter<<<(E + B - 1) / B, B, 0, stream>>>(row, col, val, dinv, col_ptr, col_cnt8, rank, srt_rp, E, N);
    k_x1<<<(N + B - 1) / B, B, 0, stream>>>(col_ptr, srt_rp, pv_self, x1, N);
    k_gather_x1<<<(E + B - 1) / B, B, 0, stream>>>(srt_rp, x1, px, E);

    // conv2: scalar-form propagate, then GEMM 128->256 (fp32 out)
    k_prop2<<<(N + 1) / 2, 256, 0, stream>>>(col_ptr, px, pv_self, x1, w1, b1, p2, N);
    {
        dim3 grid((N + 63) / 64, D2 / 64);
        k_gemm_t<D1, D2, true, true, false><<<grid, 256, 0, stream>>>(p2, w2, b2, bias2, x1, h2, N);
    }

    // conv3: GEMM 256->128 -> bf16 z, then bf16 gather propagate + fused bias3/leaky
    {
        dim3 grid((N + 63) / 64, D1 / 64);
        k_gemm_t<D2, D1, false, false, true><<<grid, 256, 0, stream>>>(h2, w3, b3, nullptr, nullptr, (void*)zb, N);
    }
    k_prop3_bf16<<<(N + 3) / 4, 256, 0, stream>>>(col_ptr, srt_rp, pv_self, zb, bias3, out, N);
}